// Round 13
// baseline (31.568 us; speedup 1.0000x reference)
//
#include <hip/hip_runtime.h>
#include <hip/hip_bf16.h>

#define B_TOTAL 2048
#define IN_SZ   288
#define GH      64
#define E_NUM   8
#define OUT_N   256
#define NKT     9                 // k-tiles of 32 per expert

#define W2T_BLKS 576              // 8 e x 9 kt x 8 og, one 32x32 tile each
#define ZF_BLKS  32               // 64 rows each (4 waves x 16)
#define GWF_BLKS 4
#define GWF_FRAGS 46              // 36 g0 + 8 g1 + 2 g2

typedef __attribute__((ext_vector_type(8))) short bf16x8;
typedef __attribute__((ext_vector_type(4))) float f32x4;

__device__ __forceinline__ float elu_f(float x) {
    return x > 0.0f ? x : (expf(x) - 1.0f);
}
__device__ __forceinline__ ushort f2bf(float f) {
    __hip_bfloat16 h = __float2bfloat16(f);
    return *reinterpret_cast<ushort*>(&h);
}

// ================= k1: build ALL fragment-major operands (r12 verbatim) =================
__global__ __launch_bounds__(256) void prep_kernel(
    const float* __restrict__ w2, const float* __restrict__ z,
    const float* __restrict__ g0_w, const float* __restrict__ g1_w,
    const float* __restrict__ g2_w,
    ushort* __restrict__ w2f, ushort* __restrict__ zf, ushort* __restrict__ gwf)
{
    __shared__ float ts[32][36];
    const int t = threadIdx.x;
    const int wid = t >> 6, l = t & 63;
    const int fr = l & 15, fg = l >> 4;

    if (blockIdx.x < W2T_BLKS) {
        const int e  = blockIdx.x / 72;
        const int r_ = blockIdx.x - e * 72;
        const int kt = r_ >> 3;
        const int og = r_ & 7;
        const int o0 = og * 32;
        const float* src = w2 + ((size_t)e * IN_SZ + kt * 32) * OUT_N + o0;
        {
            int r = t >> 3, c4 = t & 7;
            *(float4*)&ts[r][c4 * 4] = *(const float4*)(src + (size_t)r * OUT_N + c4 * 4);
        }
        __syncthreads();
        {
            const int fl   = t >> 7;
            const int half = (t >> 6) & 1;
            const int ll   = t & 63;
            const int qfr = ll & 15, qfg = ll >> 4;
            const int nt = og * 2 + fl;
            ushort4 u;
            u.x = f2bf(ts[qfg * 8 + half * 4 + 0][fl * 16 + qfr]);
            u.y = f2bf(ts[qfg * 8 + half * 4 + 1][fl * 16 + qfr]);
            u.z = f2bf(ts[qfg * 8 + half * 4 + 2][fl * 16 + qfr]);
            u.w = f2bf(ts[qfg * 8 + half * 4 + 3][fl * 16 + qfr]);
            size_t off = ((size_t)((e * 16 + nt) * NKT + kt)) * 512 + ll * 8 + half * 4;
            *(ushort4*)&w2f[off] = u;
        }
        return;
    }

    if (blockIdx.x < W2T_BLKS + ZF_BLKS) {
        const int mt = (blockIdx.x - W2T_BLKS) * 4 + wid;
        const int m0 = mt * 16;
        const float* zr = z + (size_t)(m0 + fr) * IN_SZ + fg * 8;
        #pragma unroll
        for (int kt = 0; kt < NKT; ++kt) {
            float4 v0 = *(const float4*)(zr + kt * 32);
            float4 v1 = *(const float4*)(zr + kt * 32 + 4);
            ushort4 u0, u1;
            u0.x = f2bf(v0.x); u0.y = f2bf(v0.y); u0.z = f2bf(v0.z); u0.w = f2bf(v0.w);
            u1.x = f2bf(v1.x); u1.y = f2bf(v1.y); u1.z = f2bf(v1.z); u1.w = f2bf(v1.w);
            size_t off = ((size_t)(mt * NKT + kt)) * 512 + l * 8;
            *(ushort4*)&zf[off]     = u0;
            *(ushort4*)&zf[off + 4] = u1;
        }
        return;
    }

    const int base = (blockIdx.x - W2T_BLKS - ZF_BLKS) * 4 + wid;
    for (int fid = base; fid < GWF_FRAGS; fid += 16) {
        float vals[8];
        if (fid < 36) {
            int nt = fid / NKT, kt = fid - nt * NKT;
            #pragma unroll
            for (int j = 0; j < 8; ++j) {
                int k = kt * 32 + fg * 8 + j;
                vals[j] = g0_w[k * GH + nt * 16 + fr];
            }
        } else if (fid < 44) {
            int q = fid - 36, nt = q >> 1, kk = q & 1;
            #pragma unroll
            for (int j = 0; j < 8; ++j) {
                int k = kk * 32 + fg * 8 + j;
                vals[j] = g1_w[k * GH + nt * 16 + fr];
            }
        } else {
            int kk = fid - 44;
            #pragma unroll
            for (int j = 0; j < 8; ++j) {
                int k = kk * 32 + fg * 8 + j;
                vals[j] = (fr < E_NUM) ? g2_w[k * E_NUM + fr] : 0.0f;
            }
        }
        ushort4 u0, u1;
        u0.x = f2bf(vals[0]); u0.y = f2bf(vals[1]); u0.z = f2bf(vals[2]); u0.w = f2bf(vals[3]);
        u1.x = f2bf(vals[4]); u1.y = f2bf(vals[5]); u1.z = f2bf(vals[6]); u1.w = f2bf(vals[7]);
        size_t off = (size_t)fid * 512 + l * 8;
        *(ushort4*)&gwf[off]     = u0;
        *(ushort4*)&gwf[off + 4] = u1;
    }
}

// ================= k2: fused gate + GEMM, 4 waves, LDS-shared B (dbuf) =================
// grid (32, 16), 256 thr. Wave wv owns mt = bx*4+wv (16 rows x 16 cols).
// 4 waves cooperatively stage each expert-pair's 18 B-frags (18KB) into LDS dbuf;
// B L2 traffic /4 vs r11. First pair preloaded before gate (latency hides under it).
__global__ __launch_bounds__(256) void fused_kernel(
    const ushort* __restrict__ zf, const ushort* __restrict__ w2f,
    const ushort* __restrict__ gwf,
    const float* __restrict__ g0_b, const float* __restrict__ g1_b,
    const float* __restrict__ g2_b, const float* __restrict__ b2,
    float* __restrict__ out)
{
    __shared__ ushort Bl[2][18 * 512];     // 2 x 18432 B
    __shared__ ushort hscr[4][16][72];
    __shared__ float  lgs[4][16][8];
    __shared__ float  cfsT[4][E_NUM][16];

    const int t = threadIdx.x, wv = t >> 6, l = t & 63;
    const int fr = l & 15, fg = l >> 4, fk = fg * 8;
    const int mt = blockIdx.x * 4 + wv, m0 = mt * 16;
    const int nt = blockIdx.y, n0 = nt * 16;

    // A fragments (gate layer0 + main GEMM)
    bf16x8 A[9];
    #pragma unroll
    for (int kt = 0; kt < NKT; ++kt)
        A[kt] = *(const bf16x8*)(zf + ((size_t)(mt * NKT + kt)) * 512 + l * 8);

    // ---- preload B pair 0 (experts 0,1) into registers; latency hides under gate ----
    const int4* w2f_i4 = (const int4*)w2f;
    int4 st[5];
    #pragma unroll
    for (int it = 0; it < 5; ++it) {
        int s = t + it * 256;
        if (s < 1152) {
            int f = s >> 6, ll = s & 63;
            int el = (f >= 9) ? 1 : 0, ktf = f - 9 * el;
            st[it] = w2f_i4[((size_t)((el * 16 + nt) * NKT + ktf)) * 64 + ll];
        }
    }

    // ---- gate layer 0 (r11-validated) ----
    #pragma unroll
    for (int ng = 0; ng < 4; ++ng) {
        f32x4 g = {0.f, 0.f, 0.f, 0.f};
        #pragma unroll
        for (int kt = 0; kt < NKT; ++kt) {
            bf16x8 b = *(const bf16x8*)(gwf + ((size_t)(ng * NKT + kt)) * 512 + l * 8);
            g = __builtin_amdgcn_mfma_f32_16x16x32_bf16(A[kt], b, g, 0, 0, 0);
        }
        float bias = g0_b[ng * 16 + fr];
        #pragma unroll
        for (int j = 0; j < 4; ++j)
            hscr[wv][fg * 4 + j][ng * 16 + fr] = f2bf(elu_f(g[j] + bias));
    }
    __syncthreads();

    // ---- gate layer 1 ----
    {
        bf16x8 hA[2];
        #pragma unroll
        for (int kk = 0; kk < 2; ++kk)
            hA[kk] = *(const bf16x8*)&hscr[wv][fr][kk * 32 + fk];
        f32x4 gacc[4];
        #pragma unroll
        for (int ng = 0; ng < 4; ++ng) {
            f32x4 g = {0.f, 0.f, 0.f, 0.f};
            #pragma unroll
            for (int kk = 0; kk < 2; ++kk) {
                bf16x8 b = *(const bf16x8*)(gwf + ((size_t)(36 + ng * 2 + kk)) * 512 + l * 8);
                g = __builtin_amdgcn_mfma_f32_16x16x32_bf16(hA[kk], b, g, 0, 0, 0);
            }
            gacc[ng] = g;
        }
        __syncthreads();
        #pragma unroll
        for (int ng = 0; ng < 4; ++ng) {
            float bias = g1_b[ng * 16 + fr];
            #pragma unroll
            for (int j = 0; j < 4; ++j)
                hscr[wv][fg * 4 + j][ng * 16 + fr] = f2bf(elu_f(gacc[ng][j] + bias));
        }
    }
    __syncthreads();

    // ---- gate layer 2 -> logits ----
    {
        bf16x8 hA[2];
        #pragma unroll
        for (int kk = 0; kk < 2; ++kk)
            hA[kk] = *(const bf16x8*)&hscr[wv][fr][kk * 32 + fk];
        f32x4 g = {0.f, 0.f, 0.f, 0.f};
        #pragma unroll
        for (int kk = 0; kk < 2; ++kk) {
            bf16x8 b = *(const bf16x8*)(gwf + ((size_t)(44 + kk)) * 512 + l * 8);
            g = __builtin_amdgcn_mfma_f32_16x16x32_bf16(hA[kk], b, g, 0, 0, 0);
        }
        if (fr < E_NUM) {
            float bias = g2_b[fr];
            #pragma unroll
            for (int j = 0; j < 4; ++j)
                lgs[wv][fg * 4 + j][fr] = g[j] + bias;
        }
    }
    __syncthreads();

    // ---- softmax -> cfsT[wv][e][row] ----
    if (l < 16) {
        float m = lgs[wv][l][0];
        #pragma unroll
        for (int k = 1; k < E_NUM; ++k) m = fmaxf(m, lgs[wv][l][k]);
        float s = 0.f;
        float ex[E_NUM];
        #pragma unroll
        for (int k = 0; k < E_NUM; ++k) { ex[k] = expf(lgs[wv][l][k] - m); s += ex[k]; }
        float inv = 1.0f / s;
        #pragma unroll
        for (int k = 0; k < E_NUM; ++k) cfsT[wv][k][l] = ex[k] * inv;
    }
    __syncthreads();

    // ---- main GEMM over 4 expert pairs, B via LDS double buffer ----
    f32x4 acc = {0.f, 0.f, 0.f, 0.f};

    #pragma unroll
    for (int ep = 0; ep < 4; ++ep) {
        const int buf = ep & 1;
        // store staged pair to LDS
        #pragma unroll
        for (int it = 0; it < 5; ++it) {
            int s = t + it * 256;
            if (s < 1152) ((int4*)&Bl[buf][0])[s] = st[it];
        }
        __syncthreads();
        // preload next pair
        if (ep < 3) {
            #pragma unroll
            for (int it = 0; it < 5; ++it) {
                int s = t + it * 256;
                if (s < 1152) {
                    int f = s >> 6, ll = s & 63;
                    int el = (f >= 9) ? 1 : 0, ktf = f - 9 * el;
                    int e = (ep + 1) * 2 + el;
                    st[it] = w2f_i4[((size_t)((e * 16 + nt) * NKT + ktf)) * 64 + ll];
                }
            }
        }
        // compute both experts of this pair from LDS
        #pragma unroll
        for (int el = 0; el < 2; ++el) {
            const int e = ep * 2 + el;
            const ushort* bp = &Bl[buf][el * 9 * 512] + l * 8;
            f32x4 p0 = {0.f, 0.f, 0.f, 0.f};
            f32x4 p1 = {0.f, 0.f, 0.f, 0.f};
            #pragma unroll
            for (int kt = 0; kt < NKT; ++kt) {
                bf16x8 b = *(const bf16x8*)(bp + kt * 512);
                if (kt & 1) p1 = __builtin_amdgcn_mfma_f32_16x16x32_bf16(A[kt], b, p1, 0, 0, 0);
                else        p0 = __builtin_amdgcn_mfma_f32_16x16x32_bf16(A[kt], b, p0, 0, 0, 0);
            }
            float4 cv = *(const float4*)&cfsT[wv][e][fg * 4];
            float bv  = b2[e * OUT_N + n0 + fr];
            float ca[4] = {cv.x, cv.y, cv.z, cv.w};
            #pragma unroll
            for (int j = 0; j < 4; ++j)
                acc[j] = fmaf(ca[j], p0[j] + p1[j] + bv, acc[j]);
        }
        __syncthreads();
    }

    #pragma unroll
    for (int j = 0; j < 4; ++j)
        out[(size_t)(m0 + fg * 4 + j) * OUT_N + n0 + fr] = acc[j];
}

// ================= fallback (ws too small): f32 gate + direct =================
__global__ __launch_bounds__(64) void gate_fb_kernel(
    const float* __restrict__ z,
    const float* __restrict__ g0_w, const float* __restrict__ g0_b,
    const float* __restrict__ g1_w, const float* __restrict__ g1_b,
    const float* __restrict__ g2_w, const float* __restrict__ g2_b,
    float* __restrict__ coef)
{
    __shared__ float z_s[IN_SZ];
    __shared__ float h0_s[GH];
    __shared__ float h1_s[GH];
    const int b = blockIdx.x;
    const int t = threadIdx.x;
    const float* zr = z + (size_t)b * IN_SZ;
    for (int i = t; i < IN_SZ; i += 64) z_s[i] = zr[i];
    __syncthreads();
    float a0 = g0_b[t];
    for (int i = 0; i < IN_SZ; ++i) a0 = fmaf(z_s[i], g0_w[i * GH + t], a0);
    h0_s[t] = elu_f(a0);
    __syncthreads();
    float a1 = g1_b[t];
    for (int k = 0; k < GH; ++k) a1 = fmaf(h0_s[k], g1_w[k * GH + t], a1);
    h1_s[t] = elu_f(a1);
    __syncthreads();
    if (t < E_NUM) {
        float lg = g2_b[t];
        for (int k = 0; k < GH; ++k) lg = fmaf(h1_s[k], g2_w[k * E_NUM + t], lg);
        float m = lg;
        for (int d = 1; d < 8; d <<= 1) m = fmaxf(m, __shfl_xor(m, d, 8));
        float ex = expf(lg - m);
        float s = ex;
        for (int d = 1; d < 8; d <<= 1) s += __shfl_xor(s, d, 8);
        coef[b * E_NUM + t] = ex / s;
    }
}

__global__ __launch_bounds__(256) void direct_kernel(
    const float* __restrict__ z, const float* __restrict__ w2,
    const float* __restrict__ b2, const float* __restrict__ coef,
    float* __restrict__ out)
{
    __shared__ float z_s[8][IN_SZ];
    __shared__ float c_s[8][E_NUM];
    const int b0 = blockIdx.x * 8;
    const int t  = threadIdx.x;
    for (int idx = t; idx < 8 * IN_SZ; idx += 256)
        ((float*)z_s)[idx] = z[(size_t)b0 * IN_SZ + idx];
    if (t < 64) c_s[t >> 3][t & 7] = coef[b0 * E_NUM + t];
    __syncthreads();
    float outv[8];
    #pragma unroll
    for (int r = 0; r < 8; ++r) outv[r] = 0.0f;
    for (int e = 0; e < E_NUM; ++e) {
        const float* w = w2 + (size_t)e * IN_SZ * OUT_N + t;
        float tmp[8];
        #pragma unroll
        for (int r = 0; r < 8; ++r) tmp[r] = 0.0f;
        #pragma unroll 4
        for (int i = 0; i < IN_SZ; ++i) {
            float wv = w[i * OUT_N];
            #pragma unroll
            for (int r = 0; r < 8; ++r) tmp[r] += z_s[r][i] * wv;
        }
        float bv = b2[e * OUT_N + t];
        #pragma unroll
        for (int r = 0; r < 8; ++r) outv[r] += c_s[r][e] * (tmp[r] + bv);
    }
    #pragma unroll
    for (int r = 0; r < 8; ++r) out[(size_t)(b0 + r) * OUT_N + t] = outv[r];
}

extern "C" void kernel_launch(void* const* d_in, const int* in_sizes, int n_in,
                              void* d_out, int out_size, void* d_ws, size_t ws_size,
                              hipStream_t stream) {
    const float* z    = (const float*)d_in[0];
    const float* g0_w = (const float*)d_in[1];
    const float* g0_b = (const float*)d_in[2];
    const float* g1_w = (const float*)d_in[3];
    const float* g1_b = (const float*)d_in[4];
    const float* g2_w = (const float*)d_in[5];
    const float* g2_b = (const float*)d_in[6];
    // d_in[7..10] = w0,b0,w1,b1 are dead in the reference (layer_out never fed back)
    const float* w2   = (const float*)d_in[11];
    const float* b2   = (const float*)d_in[12];
    float* out = (float*)d_out;

    const size_t w2f_b = (size_t)E_NUM * 16 * NKT * 1024;          // 1.18 MB
    const size_t zf_b  = (size_t)128 * NKT * 1024;                 // 1.18 MB
    const size_t gwf_b = (size_t)GWF_FRAGS * 1024;                 // 47 KB

    char* p = (char*)d_ws;
    ushort* w2f = (ushort*)p;            p += w2f_b;
    ushort* zf  = (ushort*)p;            p += zf_b;
    ushort* gwf = (ushort*)p;

    if (ws_size >= w2f_b + zf_b + gwf_b) {
        prep_kernel<<<W2T_BLKS + ZF_BLKS + GWF_BLKS, 256, 0, stream>>>(
            w2, z, g0_w, g1_w, g2_w, w2f, zf, gwf);
        fused_kernel<<<dim3(B_TOTAL / 64, OUT_N / 16), 256, 0, stream>>>(
            zf, w2f, gwf, g0_b, g1_b, g2_b, b2, out);
    } else {
        float* coef = (float*)d_ws;
        gate_fb_kernel<<<B_TOTAL, 64, 0, stream>>>(z, g0_w, g0_b, g1_w, g1_b,
                                                   g2_w, g2_b, coef);
        direct_kernel<<<B_TOTAL / 8, 256, 0, stream>>>(z, w2, b2, coef, out);
    }
}

// Round 14
// 21.078 us; speedup vs baseline: 1.4976x; 1.4976x over previous
//
#include <hip/hip_runtime.h>
#include <hip/hip_bf16.h>

#define B_TOTAL 2048
#define IN_SZ   288
#define GH      64
#define E_NUM   8
#define OUT_N   256
#define NKT     9                 // k-tiles of 32 per expert

#define W2T_BLKS 576              // 8 e x 9 kt x 8 og, one 32x32 tile each
#define ZF_BLKS  32               // 64 rows each (4 waves x 16)
#define GWF_BLKS 4
#define GWF_FRAGS 46              // 36 g0 + 8 g1 + 2 g2

typedef __attribute__((ext_vector_type(8))) short bf16x8;
typedef __attribute__((ext_vector_type(4))) float f32x4;

__device__ __forceinline__ float elu_f(float x) {
    return x > 0.0f ? x : (expf(x) - 1.0f);
}
__device__ __forceinline__ ushort f2bf(float f) {
    __hip_bfloat16 h = __float2bfloat16(f);
    return *reinterpret_cast<ushort*>(&h);
}

// ================= k1: build ALL fragment-major operands (r12 verbatim) =================
__global__ __launch_bounds__(256) void prep_kernel(
    const float* __restrict__ w2, const float* __restrict__ z,
    const float* __restrict__ g0_w, const float* __restrict__ g1_w,
    const float* __restrict__ g2_w,
    ushort* __restrict__ w2f, ushort* __restrict__ zf, ushort* __restrict__ gwf)
{
    __shared__ float ts[32][36];
    const int t = threadIdx.x;
    const int wid = t >> 6, l = t & 63;
    const int fr = l & 15, fg = l >> 4;

    if (blockIdx.x < W2T_BLKS) {
        const int e  = blockIdx.x / 72;
        const int r_ = blockIdx.x - e * 72;
        const int kt = r_ >> 3;
        const int og = r_ & 7;
        const int o0 = og * 32;
        const float* src = w2 + ((size_t)e * IN_SZ + kt * 32) * OUT_N + o0;
        {
            int r = t >> 3, c4 = t & 7;
            *(float4*)&ts[r][c4 * 4] = *(const float4*)(src + (size_t)r * OUT_N + c4 * 4);
        }
        __syncthreads();
        {
            const int fl   = t >> 7;
            const int half = (t >> 6) & 1;
            const int ll   = t & 63;
            const int qfr = ll & 15, qfg = ll >> 4;
            const int nt = og * 2 + fl;
            ushort4 u;
            u.x = f2bf(ts[qfg * 8 + half * 4 + 0][fl * 16 + qfr]);
            u.y = f2bf(ts[qfg * 8 + half * 4 + 1][fl * 16 + qfr]);
            u.z = f2bf(ts[qfg * 8 + half * 4 + 2][fl * 16 + qfr]);
            u.w = f2bf(ts[qfg * 8 + half * 4 + 3][fl * 16 + qfr]);
            size_t off = ((size_t)((e * 16 + nt) * NKT + kt)) * 512 + ll * 8 + half * 4;
            *(ushort4*)&w2f[off] = u;
        }
        return;
    }

    if (blockIdx.x < W2T_BLKS + ZF_BLKS) {
        const int mt = (blockIdx.x - W2T_BLKS) * 4 + wid;
        const int m0 = mt * 16;
        const float* zr = z + (size_t)(m0 + fr) * IN_SZ + fg * 8;
        #pragma unroll
        for (int kt = 0; kt < NKT; ++kt) {
            float4 v0 = *(const float4*)(zr + kt * 32);
            float4 v1 = *(const float4*)(zr + kt * 32 + 4);
            ushort4 u0, u1;
            u0.x = f2bf(v0.x); u0.y = f2bf(v0.y); u0.z = f2bf(v0.z); u0.w = f2bf(v0.w);
            u1.x = f2bf(v1.x); u1.y = f2bf(v1.y); u1.z = f2bf(v1.z); u1.w = f2bf(v1.w);
            size_t off = ((size_t)(mt * NKT + kt)) * 512 + l * 8;
            *(ushort4*)&zf[off]     = u0;
            *(ushort4*)&zf[off + 4] = u1;
        }
        return;
    }

    const int base = (blockIdx.x - W2T_BLKS - ZF_BLKS) * 4 + wid;
    for (int fid = base; fid < GWF_FRAGS; fid += 16) {
        float vals[8];
        if (fid < 36) {
            int nt = fid / NKT, kt = fid - nt * NKT;
            #pragma unroll
            for (int j = 0; j < 8; ++j) {
                int k = kt * 32 + fg * 8 + j;
                vals[j] = g0_w[k * GH + nt * 16 + fr];
            }
        } else if (fid < 44) {
            int q = fid - 36, nt = q >> 1, kk = q & 1;
            #pragma unroll
            for (int j = 0; j < 8; ++j) {
                int k = kk * 32 + fg * 8 + j;
                vals[j] = g1_w[k * GH + nt * 16 + fr];
            }
        } else {
            int kk = fid - 44;
            #pragma unroll
            for (int j = 0; j < 8; ++j) {
                int k = kk * 32 + fg * 8 + j;
                vals[j] = (fr < E_NUM) ? g2_w[k * E_NUM + fr] : 0.0f;
            }
        }
        ushort4 u0, u1;
        u0.x = f2bf(vals[0]); u0.y = f2bf(vals[1]); u0.z = f2bf(vals[2]); u0.w = f2bf(vals[3]);
        u1.x = f2bf(vals[4]); u1.y = f2bf(vals[5]); u1.z = f2bf(vals[6]); u1.w = f2bf(vals[7]);
        size_t off = (size_t)fid * 512 + l * 8;
        *(ushort4*)&gwf[off]     = u0;
        *(ushort4*)&gwf[off + 4] = u1;
    }
}

// ================= k2: fused gate + GEMM; gate computed ONCE per block =================
// grid (128, 4), 256 thr = 4 waves. All waves share mt = blockIdx.x (same A-frags);
// wave wv owns nt = blockIdx.y*4 + wv. Gate layers split across waves (ng = wv),
// exchanged via 3 KB LDS; GEMM phase is r11's barrier-free independent-chain loop.
__global__ __launch_bounds__(256) void fused_kernel(
    const ushort* __restrict__ zf, const ushort* __restrict__ w2f,
    const ushort* __restrict__ gwf,
    const float* __restrict__ g0_b, const float* __restrict__ g1_b,
    const float* __restrict__ g2_b, const float* __restrict__ b2,
    float* __restrict__ out)
{
    __shared__ ushort hscr[16][72];
    __shared__ float  lgs[16][8];
    __shared__ float  cfsT[E_NUM][16];

    const int t = threadIdx.x, wv = t >> 6, l = t & 63;
    const int fr = l & 15, fg = l >> 4, fk = fg * 8;
    const int mt = blockIdx.x, m0 = mt * 16;
    const int nt = blockIdx.y * 4 + wv, n0 = nt * 16;

    // A fragments — same for all 4 waves (L1-shared), used by gate L0 and GEMM
    bf16x8 A[9];
    #pragma unroll
    for (int kt = 0; kt < NKT; ++kt)
        A[kt] = *(const bf16x8*)(zf + ((size_t)(mt * NKT + kt)) * 512 + l * 8);

    // ---- gate layer 0: wave wv computes output-column slice ng = wv ----
    {
        f32x4 g = {0.f, 0.f, 0.f, 0.f};
        #pragma unroll
        for (int kt = 0; kt < NKT; ++kt) {
            bf16x8 b = *(const bf16x8*)(gwf + ((size_t)(wv * NKT + kt)) * 512 + l * 8);
            g = __builtin_amdgcn_mfma_f32_16x16x32_bf16(A[kt], b, g, 0, 0, 0);
        }
        float bias = g0_b[wv * 16 + fr];
        #pragma unroll
        for (int j = 0; j < 4; ++j)
            hscr[fg * 4 + j][wv * 16 + fr] = f2bf(elu_f(g[j] + bias));
    }
    __syncthreads();

    // ---- gate layer 1: read full h0, wave wv computes slice ng = wv ----
    {
        bf16x8 hA[2];
        #pragma unroll
        for (int kk = 0; kk < 2; ++kk)
            hA[kk] = *(const bf16x8*)&hscr[fr][kk * 32 + fk];
        f32x4 g = {0.f, 0.f, 0.f, 0.f};
        #pragma unroll
        for (int kk = 0; kk < 2; ++kk) {
            bf16x8 b = *(const bf16x8*)(gwf + ((size_t)(36 + wv * 2 + kk)) * 512 + l * 8);
            g = __builtin_amdgcn_mfma_f32_16x16x32_bf16(hA[kk], b, g, 0, 0, 0);
        }
        __syncthreads();    // all hA reads done before h1 overwrites
        float bias = g1_b[wv * 16 + fr];
        #pragma unroll
        for (int j = 0; j < 4; ++j)
            hscr[fg * 4 + j][wv * 16 + fr] = f2bf(elu_f(g[j] + bias));
    }
    __syncthreads();

    // ---- gate layer 2 (wave 0 only) -> logits ----
    if (wv == 0) {
        bf16x8 hA[2];
        #pragma unroll
        for (int kk = 0; kk < 2; ++kk)
            hA[kk] = *(const bf16x8*)&hscr[fr][kk * 32 + fk];
        f32x4 g = {0.f, 0.f, 0.f, 0.f};
        #pragma unroll
        for (int kk = 0; kk < 2; ++kk) {
            bf16x8 b = *(const bf16x8*)(gwf + ((size_t)(44 + kk)) * 512 + l * 8);
            g = __builtin_amdgcn_mfma_f32_16x16x32_bf16(hA[kk], b, g, 0, 0, 0);
        }
        if (fr < E_NUM) {
            float bias = g2_b[fr];
            #pragma unroll
            for (int j = 0; j < 4; ++j)
                lgs[fg * 4 + j][fr] = g[j] + bias;
        }
    }
    __syncthreads();

    // ---- softmax (threads 0..15) -> cfsT[e][row] ----
    if (t < 16) {
        float m = lgs[t][0];
        #pragma unroll
        for (int k = 1; k < E_NUM; ++k) m = fmaxf(m, lgs[t][k]);
        float s = 0.f;
        float ex[E_NUM];
        #pragma unroll
        for (int k = 0; k < E_NUM; ++k) { ex[k] = expf(lgs[t][k] - m); s += ex[k]; }
        float inv = 1.0f / s;
        #pragma unroll
        for (int k = 0; k < E_NUM; ++k) cfsT[k][t] = ex[k] * inv;
    }
    __syncthreads();

    // ---- main GEMM (r11-validated): per-expert partials, independent chains ----
    const ushort* Bp = w2f + (size_t)nt * NKT * 512 + l * 8;

    f32x4 acc = {0.f, 0.f, 0.f, 0.f};
    bf16x8 B[9];
    #pragma unroll
    for (int kt = 0; kt < NKT; ++kt)
        B[kt] = *(const bf16x8*)(Bp + (size_t)kt * 512);

    #pragma unroll
    for (int e = 0; e < E_NUM; ++e) {
        bf16x8 Bn[9];
        if (e < E_NUM - 1) {
            #pragma unroll
            for (int kt = 0; kt < NKT; ++kt)
                Bn[kt] = *(const bf16x8*)(Bp + ((size_t)((e + 1) * 16 * NKT) + kt) * 512);
        }
        f32x4 p0 = {0.f, 0.f, 0.f, 0.f};
        f32x4 p1 = {0.f, 0.f, 0.f, 0.f};
        p0 = __builtin_amdgcn_mfma_f32_16x16x32_bf16(A[0], B[0], p0, 0, 0, 0);
        p1 = __builtin_amdgcn_mfma_f32_16x16x32_bf16(A[1], B[1], p1, 0, 0, 0);
        p0 = __builtin_amdgcn_mfma_f32_16x16x32_bf16(A[2], B[2], p0, 0, 0, 0);
        p1 = __builtin_amdgcn_mfma_f32_16x16x32_bf16(A[3], B[3], p1, 0, 0, 0);
        p0 = __builtin_amdgcn_mfma_f32_16x16x32_bf16(A[4], B[4], p0, 0, 0, 0);
        p1 = __builtin_amdgcn_mfma_f32_16x16x32_bf16(A[5], B[5], p1, 0, 0, 0);
        p0 = __builtin_amdgcn_mfma_f32_16x16x32_bf16(A[6], B[6], p0, 0, 0, 0);
        p1 = __builtin_amdgcn_mfma_f32_16x16x32_bf16(A[7], B[7], p1, 0, 0, 0);
        p0 = __builtin_amdgcn_mfma_f32_16x16x32_bf16(A[8], B[8], p0, 0, 0, 0);

        float4 cv = *(const float4*)&cfsT[e][fg * 4];
        float bv  = b2[e * OUT_N + n0 + fr];
        float ca[4] = {cv.x, cv.y, cv.z, cv.w};
        #pragma unroll
        for (int j = 0; j < 4; ++j)
            acc[j] = fmaf(ca[j], p0[j] + p1[j] + bv, acc[j]);

        #pragma unroll
        for (int kt = 0; kt < NKT; ++kt) B[kt] = Bn[kt];
    }

    #pragma unroll
    for (int j = 0; j < 4; ++j)
        out[(size_t)(m0 + fg * 4 + j) * OUT_N + n0 + fr] = acc[j];
}

// ================= fallback (ws too small): f32 gate + direct =================
__global__ __launch_bounds__(64) void gate_fb_kernel(
    const float* __restrict__ z,
    const float* __restrict__ g0_w, const float* __restrict__ g0_b,
    const float* __restrict__ g1_w, const float* __restrict__ g1_b,
    const float* __restrict__ g2_w, const float* __restrict__ g2_b,
    float* __restrict__ coef)
{
    __shared__ float z_s[IN_SZ];
    __shared__ float h0_s[GH];
    __shared__ float h1_s[GH];
    const int b = blockIdx.x;
    const int t = threadIdx.x;
    const float* zr = z + (size_t)b * IN_SZ;
    for (int i = t; i < IN_SZ; i += 64) z_s[i] = zr[i];
    __syncthreads();
    float a0 = g0_b[t];
    for (int i = 0; i < IN_SZ; ++i) a0 = fmaf(z_s[i], g0_w[i * GH + t], a0);
    h0_s[t] = elu_f(a0);
    __syncthreads();
    float a1 = g1_b[t];
    for (int k = 0; k < GH; ++k) a1 = fmaf(h0_s[k], g1_w[k * GH + t], a1);
    h1_s[t] = elu_f(a1);
    __syncthreads();
    if (t < E_NUM) {
        float lg = g2_b[t];
        for (int k = 0; k < GH; ++k) lg = fmaf(h1_s[k], g2_w[k * E_NUM + t], lg);
        float m = lg;
        for (int d = 1; d < 8; d <<= 1) m = fmaxf(m, __shfl_xor(m, d, 8));
        float ex = expf(lg - m);
        float s = ex;
        for (int d = 1; d < 8; d <<= 1) s += __shfl_xor(s, d, 8);
        coef[b * E_NUM + t] = ex / s;
    }
}

__global__ __launch_bounds__(256) void direct_kernel(
    const float* __restrict__ z, const float* __restrict__ w2,
    const float* __restrict__ b2, const float* __restrict__ coef,
    float* __restrict__ out)
{
    __shared__ float z_s[8][IN_SZ];
    __shared__ float c_s[8][E_NUM];
    const int b0 = blockIdx.x * 8;
    const int t  = threadIdx.x;
    for (int idx = t; idx < 8 * IN_SZ; idx += 256)
        ((float*)z_s)[idx] = z[(size_t)b0 * IN_SZ + idx];
    if (t < 64) c_s[t >> 3][t & 7] = coef[b0 * E_NUM + t];
    __syncthreads();
    float outv[8];
    #pragma unroll
    for (int r = 0; r < 8; ++r) outv[r] = 0.0f;
    for (int e = 0; e < E_NUM; ++e) {
        const float* w = w2 + (size_t)e * IN_SZ * OUT_N + t;
        float tmp[8];
        #pragma unroll
        for (int r = 0; r < 8; ++r) tmp[r] = 0.0f;
        #pragma unroll 4
        for (int i = 0; i < IN_SZ; ++i) {
            float wv = w[i * OUT_N];
            #pragma unroll
            for (int r = 0; r < 8; ++r) tmp[r] += z_s[r][i] * wv;
        }
        float bv = b2[e * OUT_N + t];
        #pragma unroll
        for (int r = 0; r < 8; ++r) outv[r] += c_s[r][e] * (tmp[r] + bv);
    }
    #pragma unroll
    for (int r = 0; r < 8; ++r) out[(size_t)(b0 + r) * OUT_N + t] = outv[r];
}

extern "C" void kernel_launch(void* const* d_in, const int* in_sizes, int n_in,
                              void* d_out, int out_size, void* d_ws, size_t ws_size,
                              hipStream_t stream) {
    const float* z    = (const float*)d_in[0];
    const float* g0_w = (const float*)d_in[1];
    const float* g0_b = (const float*)d_in[2];
    const float* g1_w = (const float*)d_in[3];
    const float* g1_b = (const float*)d_in[4];
    const float* g2_w = (const float*)d_in[5];
    const float* g2_b = (const float*)d_in[6];
    // d_in[7..10] = w0,b0,w1,b1 are dead in the reference (layer_out never fed back)
    const float* w2   = (const float*)d_in[11];
    const float* b2   = (const float*)d_in[12];
    float* out = (float*)d_out;

    const size_t w2f_b = (size_t)E_NUM * 16 * NKT * 1024;          // 1.18 MB
    const size_t zf_b  = (size_t)128 * NKT * 1024;                 // 1.18 MB
    const size_t gwf_b = (size_t)GWF_FRAGS * 1024;                 // 47 KB

    char* p = (char*)d_ws;
    ushort* w2f = (ushort*)p;            p += w2f_b;
    ushort* zf  = (ushort*)p;            p += zf_b;
    ushort* gwf = (ushort*)p;

    if (ws_size >= w2f_b + zf_b + gwf_b) {
        prep_kernel<<<W2T_BLKS + ZF_BLKS + GWF_BLKS, 256, 0, stream>>>(
            w2, z, g0_w, g1_w, g2_w, w2f, zf, gwf);
        fused_kernel<<<dim3(B_TOTAL / 16, OUT_N / 64), 256, 0, stream>>>(
            zf, w2f, gwf, g0_b, g1_b, g2_b, b2, out);
    } else {
        float* coef = (float*)d_ws;
        gate_fb_kernel<<<B_TOTAL, 64, 0, stream>>>(z, g0_w, g0_b, g1_w, g1_b,
                                                   g2_w, g2_b, coef);
        direct_kernel<<<B_TOTAL / 8, 256, 0, stream>>>(z, w2, b2, coef, out);
    }
}

// Round 15
// 19.841 us; speedup vs baseline: 1.5911x; 1.0624x over previous
//
#include <hip/hip_runtime.h>
#include <hip/hip_bf16.h>

#define B_TOTAL 2048
#define IN_SZ   288
#define GH      64
#define E_NUM   8
#define OUT_N   256
#define NKT     9                 // k-tiles of 32 per expert

#define W2T_BLKS 576              // 8 e x 9 kt x 8 og, one 32x32 tile each
#define ZF_BLKS  32               // 64 rows each (4 waves x 16)
#define GWF_BLKS 4
#define GWF_FRAGS 46              // 36 g0 + 8 g1 + 2 g2

typedef __attribute__((ext_vector_type(8))) short bf16x8;
typedef __attribute__((ext_vector_type(4))) float f32x4;

__device__ __forceinline__ float elu_f(float x) {
    return x > 0.0f ? x : (expf(x) - 1.0f);
}
__device__ __forceinline__ ushort f2bf(float f) {
    __hip_bfloat16 h = __float2bfloat16(f);
    return *reinterpret_cast<ushort*>(&h);
}

// ================= k1: build ALL fragment-major operands (r12 verbatim) =================
__global__ __launch_bounds__(256) void prep_kernel(
    const float* __restrict__ w2, const float* __restrict__ z,
    const float* __restrict__ g0_w, const float* __restrict__ g1_w,
    const float* __restrict__ g2_w,
    ushort* __restrict__ w2f, ushort* __restrict__ zf, ushort* __restrict__ gwf)
{
    __shared__ float ts[32][36];
    const int t = threadIdx.x;
    const int wid = t >> 6, l = t & 63;
    const int fr = l & 15, fg = l >> 4;

    if (blockIdx.x < W2T_BLKS) {
        const int e  = blockIdx.x / 72;
        const int r_ = blockIdx.x - e * 72;
        const int kt = r_ >> 3;
        const int og = r_ & 7;
        const int o0 = og * 32;
        const float* src = w2 + ((size_t)e * IN_SZ + kt * 32) * OUT_N + o0;
        {
            int r = t >> 3, c4 = t & 7;
            *(float4*)&ts[r][c4 * 4] = *(const float4*)(src + (size_t)r * OUT_N + c4 * 4);
        }
        __syncthreads();
        {
            const int fl   = t >> 7;
            const int half = (t >> 6) & 1;
            const int ll   = t & 63;
            const int qfr = ll & 15, qfg = ll >> 4;
            const int nt = og * 2 + fl;
            ushort4 u;
            u.x = f2bf(ts[qfg * 8 + half * 4 + 0][fl * 16 + qfr]);
            u.y = f2bf(ts[qfg * 8 + half * 4 + 1][fl * 16 + qfr]);
            u.z = f2bf(ts[qfg * 8 + half * 4 + 2][fl * 16 + qfr]);
            u.w = f2bf(ts[qfg * 8 + half * 4 + 3][fl * 16 + qfr]);
            size_t off = ((size_t)((e * 16 + nt) * NKT + kt)) * 512 + ll * 8 + half * 4;
            *(ushort4*)&w2f[off] = u;
        }
        return;
    }

    if (blockIdx.x < W2T_BLKS + ZF_BLKS) {
        const int mt = (blockIdx.x - W2T_BLKS) * 4 + wid;
        const int m0 = mt * 16;
        const float* zr = z + (size_t)(m0 + fr) * IN_SZ + fg * 8;
        #pragma unroll
        for (int kt = 0; kt < NKT; ++kt) {
            float4 v0 = *(const float4*)(zr + kt * 32);
            float4 v1 = *(const float4*)(zr + kt * 32 + 4);
            ushort4 u0, u1;
            u0.x = f2bf(v0.x); u0.y = f2bf(v0.y); u0.z = f2bf(v0.z); u0.w = f2bf(v0.w);
            u1.x = f2bf(v1.x); u1.y = f2bf(v1.y); u1.z = f2bf(v1.z); u1.w = f2bf(v1.w);
            size_t off = ((size_t)(mt * NKT + kt)) * 512 + l * 8;
            *(ushort4*)&zf[off]     = u0;
            *(ushort4*)&zf[off + 4] = u1;
        }
        return;
    }

    const int base = (blockIdx.x - W2T_BLKS - ZF_BLKS) * 4 + wid;
    for (int fid = base; fid < GWF_FRAGS; fid += 16) {
        float vals[8];
        if (fid < 36) {
            int nt = fid / NKT, kt = fid - nt * NKT;
            #pragma unroll
            for (int j = 0; j < 8; ++j) {
                int k = kt * 32 + fg * 8 + j;
                vals[j] = g0_w[k * GH + nt * 16 + fr];
            }
        } else if (fid < 44) {
            int q = fid - 36, nt = q >> 1, kk = q & 1;
            #pragma unroll
            for (int j = 0; j < 8; ++j) {
                int k = kk * 32 + fg * 8 + j;
                vals[j] = g1_w[k * GH + nt * 16 + fr];
            }
        } else {
            int kk = fid - 44;
            #pragma unroll
            for (int j = 0; j < 8; ++j) {
                int k = kk * 32 + fg * 8 + j;
                vals[j] = (fr < E_NUM) ? g2_w[k * E_NUM + fr] : 0.0f;
            }
        }
        ushort4 u0, u1;
        u0.x = f2bf(vals[0]); u0.y = f2bf(vals[1]); u0.z = f2bf(vals[2]); u0.w = f2bf(vals[3]);
        u1.x = f2bf(vals[4]); u1.y = f2bf(vals[5]); u1.z = f2bf(vals[6]); u1.w = f2bf(vals[7]);
        size_t off = (size_t)fid * 512 + l * 8;
        *(ushort4*)&gwf[off]     = u0;
        *(ushort4*)&gwf[off + 4] = u1;
    }
}

// ================= k2: fused gate + GEMM (r14 structure + latency-overlap tweaks) =================
// grid (128, 4), 256 thr = 4 waves. All waves share mt = blockIdx.x; wave wv owns
// nt = blockIdx.y*4+wv. Gate computed once per block (slices split across waves).
// NEW vs r14: expert-0 B frags + per-expert biases issued BEFORE the gate phase
// (latency hides under gate MFMAs); e-loop uses even/odd B buffers, fully unrolled
// (no register copies).
__global__ __launch_bounds__(256) void fused_kernel(
    const ushort* __restrict__ zf, const ushort* __restrict__ w2f,
    const ushort* __restrict__ gwf,
    const float* __restrict__ g0_b, const float* __restrict__ g1_b,
    const float* __restrict__ g2_b, const float* __restrict__ b2,
    float* __restrict__ out)
{
    __shared__ ushort hscr[16][72];
    __shared__ float  lgs[16][8];
    __shared__ float  cfsT[E_NUM][16];

    const int t = threadIdx.x, wv = t >> 6, l = t & 63;
    const int fr = l & 15, fg = l >> 4, fk = fg * 8;
    const int mt = blockIdx.x, m0 = mt * 16;
    const int nt = blockIdx.y * 4 + wv, n0 = nt * 16;

    // A fragments — same for all 4 waves (L1-shared), used by gate L0 and GEMM
    bf16x8 A[9];
    #pragma unroll
    for (int kt = 0; kt < NKT; ++kt)
        A[kt] = *(const bf16x8*)(zf + ((size_t)(mt * NKT + kt)) * 512 + l * 8);

    // ---- early-issue: expert-0 B fragments + all 8 bias values (hide under gate) ----
    const ushort* Bp = w2f + (size_t)nt * NKT * 512 + l * 8;
    bf16x8 Bb0[9], Bb1[9];
    #pragma unroll
    for (int kt = 0; kt < NKT; ++kt)
        Bb0[kt] = *(const bf16x8*)(Bp + (size_t)kt * 512);
    float bvv[E_NUM];
    #pragma unroll
    for (int e = 0; e < E_NUM; ++e)
        bvv[e] = b2[e * OUT_N + n0 + fr];

    // ---- gate layer 0: wave wv computes output-column slice ng = wv ----
    {
        f32x4 g = {0.f, 0.f, 0.f, 0.f};
        #pragma unroll
        for (int kt = 0; kt < NKT; ++kt) {
            bf16x8 b = *(const bf16x8*)(gwf + ((size_t)(wv * NKT + kt)) * 512 + l * 8);
            g = __builtin_amdgcn_mfma_f32_16x16x32_bf16(A[kt], b, g, 0, 0, 0);
        }
        float bias = g0_b[wv * 16 + fr];
        #pragma unroll
        for (int j = 0; j < 4; ++j)
            hscr[fg * 4 + j][wv * 16 + fr] = f2bf(elu_f(g[j] + bias));
    }
    __syncthreads();

    // ---- gate layer 1: read full h0, wave wv computes slice ng = wv ----
    {
        bf16x8 hA[2];
        #pragma unroll
        for (int kk = 0; kk < 2; ++kk)
            hA[kk] = *(const bf16x8*)&hscr[fr][kk * 32 + fk];
        f32x4 g = {0.f, 0.f, 0.f, 0.f};
        #pragma unroll
        for (int kk = 0; kk < 2; ++kk) {
            bf16x8 b = *(const bf16x8*)(gwf + ((size_t)(36 + wv * 2 + kk)) * 512 + l * 8);
            g = __builtin_amdgcn_mfma_f32_16x16x32_bf16(hA[kk], b, g, 0, 0, 0);
        }
        __syncthreads();    // all hA reads done before h1 overwrites
        float bias = g1_b[wv * 16 + fr];
        #pragma unroll
        for (int j = 0; j < 4; ++j)
            hscr[fg * 4 + j][wv * 16 + fr] = f2bf(elu_f(g[j] + bias));
    }
    __syncthreads();

    // ---- gate layer 2 (wave 0 only) -> logits ----
    if (wv == 0) {
        bf16x8 hA[2];
        #pragma unroll
        for (int kk = 0; kk < 2; ++kk)
            hA[kk] = *(const bf16x8*)&hscr[fr][kk * 32 + fk];
        f32x4 g = {0.f, 0.f, 0.f, 0.f};
        #pragma unroll
        for (int kk = 0; kk < 2; ++kk) {
            bf16x8 b = *(const bf16x8*)(gwf + ((size_t)(44 + kk)) * 512 + l * 8);
            g = __builtin_amdgcn_mfma_f32_16x16x32_bf16(hA[kk], b, g, 0, 0, 0);
        }
        if (fr < E_NUM) {
            float bias = g2_b[fr];
            #pragma unroll
            for (int j = 0; j < 4; ++j)
                lgs[fg * 4 + j][fr] = g[j] + bias;
        }
    }
    __syncthreads();

    // ---- softmax (threads 0..15) -> cfsT[e][row] ----
    if (t < 16) {
        float m = lgs[t][0];
        #pragma unroll
        for (int k = 1; k < E_NUM; ++k) m = fmaxf(m, lgs[t][k]);
        float s = 0.f;
        float ex[E_NUM];
        #pragma unroll
        for (int k = 0; k < E_NUM; ++k) { ex[k] = expf(lgs[t][k] - m); s += ex[k]; }
        float inv = 1.0f / s;
        #pragma unroll
        for (int k = 0; k < E_NUM; ++k) cfsT[k][t] = ex[k] * inv;
    }
    __syncthreads();

    // ---- main GEMM: even/odd B buffers, fully unrolled, no register copies ----
    f32x4 acc = {0.f, 0.f, 0.f, 0.f};

    #pragma unroll
    for (int e = 0; e < E_NUM; ++e) {
        // prefetch next expert into the other buffer (compile-time selected)
        if (e < E_NUM - 1) {
            #pragma unroll
            for (int kt = 0; kt < NKT; ++kt) {
                bf16x8 v = *(const bf16x8*)(Bp + ((size_t)((e + 1) * 16 * NKT) + kt) * 512);
                if (e & 1) Bb0[kt] = v; else Bb1[kt] = v;
            }
        }
        f32x4 p0 = {0.f, 0.f, 0.f, 0.f};
        f32x4 p1 = {0.f, 0.f, 0.f, 0.f};
        #pragma unroll
        for (int kt = 0; kt < NKT; ++kt) {
            bf16x8 b = (e & 1) ? Bb1[kt] : Bb0[kt];   // compile-time select (e unrolled)
            if (kt & 1) p1 = __builtin_amdgcn_mfma_f32_16x16x32_bf16(A[kt], b, p1, 0, 0, 0);
            else        p0 = __builtin_amdgcn_mfma_f32_16x16x32_bf16(A[kt], b, p0, 0, 0, 0);
        }
        float4 cv = *(const float4*)&cfsT[e][fg * 4];
        float ca[4] = {cv.x, cv.y, cv.z, cv.w};
        #pragma unroll
        for (int j = 0; j < 4; ++j)
            acc[j] = fmaf(ca[j], p0[j] + p1[j] + bvv[e], acc[j]);
    }

    #pragma unroll
    for (int j = 0; j < 4; ++j)
        out[(size_t)(m0 + fg * 4 + j) * OUT_N + n0 + fr] = acc[j];
}

// ================= fallback (ws too small): f32 gate + direct =================
__global__ __launch_bounds__(64) void gate_fb_kernel(
    const float* __restrict__ z,
    const float* __restrict__ g0_w, const float* __restrict__ g0_b,
    const float* __restrict__ g1_w, const float* __restrict__ g1_b,
    const float* __restrict__ g2_w, const float* __restrict__ g2_b,
    float* __restrict__ coef)
{
    __shared__ float z_s[IN_SZ];
    __shared__ float h0_s[GH];
    __shared__ float h1_s[GH];
    const int b = blockIdx.x;
    const int t = threadIdx.x;
    const float* zr = z + (size_t)b * IN_SZ;
    for (int i = t; i < IN_SZ; i += 64) z_s[i] = zr[i];
    __syncthreads();
    float a0 = g0_b[t];
    for (int i = 0; i < IN_SZ; ++i) a0 = fmaf(z_s[i], g0_w[i * GH + t], a0);
    h0_s[t] = elu_f(a0);
    __syncthreads();
    float a1 = g1_b[t];
    for (int k = 0; k < GH; ++k) a1 = fmaf(h0_s[k], g1_w[k * GH + t], a1);
    h1_s[t] = elu_f(a1);
    __syncthreads();
    if (t < E_NUM) {
        float lg = g2_b[t];
        for (int k = 0; k < GH; ++k) lg = fmaf(h1_s[k], g2_w[k * E_NUM + t], lg);
        float m = lg;
        for (int d = 1; d < 8; d <<= 1) m = fmaxf(m, __shfl_xor(m, d, 8));
        float ex = expf(lg - m);
        float s = ex;
        for (int d = 1; d < 8; d <<= 1) s += __shfl_xor(s, d, 8);
        coef[b * E_NUM + t] = ex / s;
    }
}

__global__ __launch_bounds__(256) void direct_kernel(
    const float* __restrict__ z, const float* __restrict__ w2,
    const float* __restrict__ b2, const float* __restrict__ coef,
    float* __restrict__ out)
{
    __shared__ float z_s[8][IN_SZ];
    __shared__ float c_s[8][E_NUM];
    const int b0 = blockIdx.x * 8;
    const int t  = threadIdx.x;
    for (int idx = t; idx < 8 * IN_SZ; idx += 256)
        ((float*)z_s)[idx] = z[(size_t)b0 * IN_SZ + idx];
    if (t < 64) c_s[t >> 3][t & 7] = coef[b0 * E_NUM + t];
    __syncthreads();
    float outv[8];
    #pragma unroll
    for (int r = 0; r < 8; ++r) outv[r] = 0.0f;
    for (int e = 0; e < E_NUM; ++e) {
        const float* w = w2 + (size_t)e * IN_SZ * OUT_N + t;
        float tmp[8];
        #pragma unroll
        for (int r = 0; r < 8; ++r) tmp[r] = 0.0f;
        #pragma unroll 4
        for (int i = 0; i < IN_SZ; ++i) {
            float wv = w[i * OUT_N];
            #pragma unroll
            for (int r = 0; r < 8; ++r) tmp[r] += z_s[r][i] * wv;
        }
        float bv = b2[e * OUT_N + t];
        #pragma unroll
        for (int r = 0; r < 8; ++r) outv[r] += c_s[r][e] * (tmp[r] + bv);
    }
    #pragma unroll
    for (int r = 0; r < 8; ++r) out[(size_t)(b0 + r) * OUT_N + t] = outv[r];
}

extern "C" void kernel_launch(void* const* d_in, const int* in_sizes, int n_in,
                              void* d_out, int out_size, void* d_ws, size_t ws_size,
                              hipStream_t stream) {
    const float* z    = (const float*)d_in[0];
    const float* g0_w = (const float*)d_in[1];
    const float* g0_b = (const float*)d_in[2];
    const float* g1_w = (const float*)d_in[3];
    const float* g1_b = (const float*)d_in[4];
    const float* g2_w = (const float*)d_in[5];
    const float* g2_b = (const float*)d_in[6];
    // d_in[7..10] = w0,b0,w1,b1 are dead in the reference (layer_out never fed back)
    const float* w2   = (const float*)d_in[11];
    const float* b2   = (const float*)d_in[12];
    float* out = (float*)d_out;

    const size_t w2f_b = (size_t)E_NUM * 16 * NKT * 1024;          // 1.18 MB
    const size_t zf_b  = (size_t)128 * NKT * 1024;                 // 1.18 MB
    const size_t gwf_b = (size_t)GWF_FRAGS * 1024;                 // 47 KB

    char* p = (char*)d_ws;
    ushort* w2f = (ushort*)p;            p += w2f_b;
    ushort* zf  = (ushort*)p;            p += zf_b;
    ushort* gwf = (ushort*)p;

    if (ws_size >= w2f_b + zf_b + gwf_b) {
        prep_kernel<<<W2T_BLKS + ZF_BLKS + GWF_BLKS, 256, 0, stream>>>(
            w2, z, g0_w, g1_w, g2_w, w2f, zf, gwf);
        fused_kernel<<<dim3(B_TOTAL / 16, OUT_N / 64), 256, 0, stream>>>(
            zf, w2f, gwf, g0_b, g1_b, g2_b, b2, out);
    } else {
        float* coef = (float*)d_ws;
        gate_fb_kernel<<<B_TOTAL, 64, 0, stream>>>(z, g0_w, g0_b, g1_w, g1_b,
                                                   g2_w, g2_b, coef);
        direct_kernel<<<B_TOTAL / 8, 256, 0, stream>>>(z, w2, b2, coef, out);
    }
}